// Round 8
// baseline (903.262 us; speedup 1.0000x reference)
//
#include <hip/hip_runtime.h>
#include <hip/hip_bf16.h>
#include <stdint.h>

// Problem constants (QuantizedLinear_15985868276124)
#define IN_F   4096
#define OUT_F  11008
#define M_TOK  8192                  // 4 * 2048 tokens
#define NGRP   (OUT_F * (IN_F / 8)) // 5,636,096 groups of 8 weights

typedef __attribute__((ext_vector_type(8))) short short8;
typedef __attribute__((ext_vector_type(4))) float f32x4;

// ---------- helpers ----------

__device__ __forceinline__ unsigned short bf16_rne(float f) {
    union { float f; uint32_t u; } v; v.f = f;
    uint32_t r = v.u + 0x7FFFu + ((v.u >> 16) & 1u); // round-to-nearest-even
    return (unsigned short)(r >> 16);
}

// ---------- kernel 1: dequantize W -> bf16 [OUT_F][IN_F] ----------
__global__ __launch_bounds__(256) void k_dequant(
        const int* __restrict__ codes,
        const float* __restrict__ codebooks,
        const float* __restrict__ scales,
        unsigned short* __restrict__ Wq) {
    __shared__ float cb[4096]; // [2][256][8]
    int tid = threadIdx.x;
    const float4* cbg = (const float4*)codebooks;
    float4* cbl = (float4*)cb;
#pragma unroll
    for (int i = 0; i < 4; ++i) cbl[tid + i * 256] = cbg[tid + i * 256];
    __syncthreads();

    int gidx = blockIdx.x * 256 + tid;      // group index in [0, NGRP)
    int o = gidx >> 9;                      // / 512
    float s = scales[o];
    int2 c = ((const int2*)codes)[gidx];

    const float4* e0 = (const float4*)&cb[c.x * 8];
    const float4* e1 = (const float4*)&cb[2048 + c.y * 8];
    float4 a0 = e0[0], a1 = e0[1];
    float4 b0 = e1[0], b1 = e1[1];

    float r[8];
    r[0] = (a0.x + b0.x) * s; r[1] = (a0.y + b0.y) * s;
    r[2] = (a0.z + b0.z) * s; r[3] = (a0.w + b0.w) * s;
    r[4] = (a1.x + b1.x) * s; r[5] = (a1.y + b1.y) * s;
    r[6] = (a1.z + b1.z) * s; r[7] = (a1.w + b1.w) * s;

    uint4 pk;
    pk.x = (uint32_t)bf16_rne(r[0]) | ((uint32_t)bf16_rne(r[1]) << 16);
    pk.y = (uint32_t)bf16_rne(r[2]) | ((uint32_t)bf16_rne(r[3]) << 16);
    pk.z = (uint32_t)bf16_rne(r[4]) | ((uint32_t)bf16_rne(r[5]) << 16);
    pk.w = (uint32_t)bf16_rne(r[6]) | ((uint32_t)bf16_rne(r[7]) << 16);
    *(uint4*)(Wq + (size_t)gidx * 8) = pk;
}

// ---------- kernel 2: x fp32 -> bf16 ----------
__global__ __launch_bounds__(256) void k_cvt(
        const float* __restrict__ x, unsigned short* __restrict__ Xq) {
    size_t i = ((size_t)blockIdx.x * 256 + threadIdx.x) * 8;
    float4 v0 = *(const float4*)(x + i);
    float4 v1 = *(const float4*)(x + i + 4);
    uint4 pk;
    pk.x = (uint32_t)bf16_rne(v0.x) | ((uint32_t)bf16_rne(v0.y) << 16);
    pk.y = (uint32_t)bf16_rne(v0.z) | ((uint32_t)bf16_rne(v0.w) << 16);
    pk.z = (uint32_t)bf16_rne(v1.x) | ((uint32_t)bf16_rne(v1.y) << 16);
    pk.w = (uint32_t)bf16_rne(v1.z) | ((uint32_t)bf16_rne(v1.w) << 16);
    *(uint4*)(Xq + i) = pk;
}

// ---------- kernel 3: 256x256 8-phase GEMM  C = Xq * Wq^T + bias ----------
// BM=BN=256, BK=64, 8 waves (2Mx4N), LDS 128 KiB.
// R8 KEY: FOUR statically distinct LDS buffers (lA0/lA1/lB0/lB1), every
// stage/read site names its buffer at COMPILE TIME. With a runtime (t&1)
// index into one array, the SIWaitcnt pass must assume every ds_read may
// alias every outstanding global_load_lds (tracked only by vmcnt) and
// drains vmcnt before each phase's reads -> 1500cyc/phase serializer seen
// in R4/R6/R7. Distinct LDS symbols => NoAlias => only cheap counted waits.

#define BARRIER() __builtin_amdgcn_s_barrier()
#define VMW(n)    asm volatile("s_waitcnt vmcnt(" #n ")")
#define LGKM8()   asm volatile("s_waitcnt lgkmcnt(8)")

#define GL16(gp, lp) __builtin_amdgcn_global_load_lds(                        \
    (const __attribute__((address_space(1))) void*)(gp),                      \
    (__attribute__((address_space(3))) void*)(lp), 16, 0, 0)

__global__ __launch_bounds__(512, 2) void k_gemm(
        const unsigned short* __restrict__ A,   // [M_TOK][IN_F] bf16
        const unsigned short* __restrict__ B,   // [OUT_F][IN_F] bf16 (B^T layout)
        const float* __restrict__ bias,
        float* __restrict__ out) {
    __shared__ unsigned short lA0[256 * 64];   // 32 KiB each
    __shared__ unsigned short lA1[256 * 64];
    __shared__ unsigned short lB0[256 * 64];
    __shared__ unsigned short lB1[256 * 64];

    const int tid = threadIdx.x;
    const int l = tid & 63;
    const int w = tid >> 6;            // wave 0..7
    const int wm = w >> 2, wn = w & 3; // 2 x 4 wave grid; wave tile 128x64

    // T1: bijective XCD swizzle. grid 1376 = 8 XCD * (4 row-chunks * 43 cols)
    int lid = blockIdx.x;
    int xcd = lid & 7, j = lid >> 3;   // j in [0,172)
    int bx = j >> 2;                   // col block 0..42 (column-major in chunk)
    int by = (xcd << 2) + (j & 3);     // row block 0..31
    const int rowBase = by * 256;
    const int colBase = bx * 256;

    // ---- staging addressing (T2: swizzle applied on GLOBAL source; LDS linear)
    // instr covers 64 rows: row = base + w*8 + (l>>3); LDS(r,cc)=global(r, cc^(r&7))
    const int srow = w * 8 + (l >> 3);
    const int scol = ((l & 7) ^ ((l >> 3) & 7)) << 3;   // swizzled element col
    const unsigned short* gA = A + (size_t)(rowBase + srow) * IN_F + scol;
    const unsigned short* gB = B + (size_t)(colBase + srow) * IN_F + scol;
    unsigned short* lA0w = &lA0[w * 8 * 64];
    unsigned short* lA1w = &lA1[w * 8 * 64];
    unsigned short* lB0w = &lB0[w * 8 * 64];
    unsigned short* lB1w = &lB1[w * 8 * 64];

    // stage one quarter of tile t into buffer P (STATIC):
    // q0/q1 = A rows {0-127, 128-255}; q2/q3 = B same
#define STAGEQ_(P, t, q) do {                                                 \
    const unsigned short* _g = (((q) < 2) ? gA : gB) + (size_t)(t) * 64;      \
    unsigned short* _l = (((q) < 2) ? lA##P##w : lB##P##w);                   \
    const int _r = ((q) & 1) * 128;                                           \
    GL16(_g + (size_t)_r * IN_F,        _l + _r * 64);                        \
    GL16(_g + (size_t)(_r + 64) * IN_F, _l + (_r + 64) * 64);                 \
} while (0)

    // ---- fragment reads (swizzled chunk = (kk*4+g) ^ (row&7), row&7 == frow&7)
    const int frow = l & 15, g = l >> 4;
    const int cho0 = ((g ^ (frow & 7)) << 4);
    const int cho1 = (((4 + g) ^ (frow & 7)) << 4);
    const char* rowA0 = (const char*)&lA0[(wm * 128 + frow) * 64];
    const char* rowA1 = (const char*)&lA1[(wm * 128 + frow) * 64];
    const char* rowB0 = (const char*)&lB0[(wn * 64 + frow) * 64];
    const char* rowB1 = (const char*)&lB1[(wn * 64 + frow) * 64];
#define LDA_(P, m, kk) (*(const short8*)(rowA##P + (m) * 2048 + ((kk) ? cho1 : cho0)))
#define LDB_(P, n, kk) (*(const short8*)(rowB##P + (n) * 2048 + ((kk) ? cho1 : cho0)))

    f32x4 acc[8][4] = {};
    short8 ar[4][2], br[4][2];

#define QUAD(M0, N0) do {                                                     \
    __builtin_amdgcn_s_setprio(1);                                            \
    _Pragma("unroll") for (int mm = 0; mm < 4; ++mm)                          \
    _Pragma("unroll") for (int nn = 0; nn < 2; ++nn)                          \
    _Pragma("unroll") for (int kk = 0; kk < 2; ++kk)                          \
        acc[(M0) + mm][(N0) + nn] = __builtin_amdgcn_mfma_f32_16x16x32_bf16(  \
            ar[mm][kk], br[(N0) + nn][kk], acc[(M0) + mm][(N0) + nn], 0, 0, 0);\
    __builtin_amdgcn_s_setprio(0);                                            \
} while (0)

#define RD_A03_B01(P) do {                                                    \
    _Pragma("unroll") for (int mm = 0; mm < 4; ++mm) {                        \
        ar[mm][0] = LDA_(P, mm, 0); ar[mm][1] = LDA_(P, mm, 1); }             \
    br[0][0] = LDB_(P, 0, 0); br[0][1] = LDB_(P, 0, 1);                       \
    br[1][0] = LDB_(P, 1, 0); br[1][1] = LDB_(P, 1, 1);                       \
} while (0)
#define RD_B23(P) do {                                                        \
    br[2][0] = LDB_(P, 2, 0); br[2][1] = LDB_(P, 2, 1);                       \
    br[3][0] = LDB_(P, 3, 0); br[3][1] = LDB_(P, 3, 1);                       \
} while (0)
#define RD_A47(P) do {                                                        \
    _Pragma("unroll") for (int mm = 0; mm < 4; ++mm) {                        \
        ar[mm][0] = LDA_(P, 4 + mm, 0); ar[mm][1] = LDA_(P, 4 + mm, 1); }     \
} while (0)

    // prologue: stage tile0 (buf0) fully + tile1 q0 (buf1); VMW(2) -> tile0 in
    STAGEQ_(0, 0, 0); STAGEQ_(0, 0, 1); STAGEQ_(0, 0, 2); STAGEQ_(0, 0, 3);
    STAGEQ_(1, 1, 0);
    VMW(2); BARRIER();

    // main loop: 2 K-tiles/iter (t=2i in buf0, t+1 in buf1); i = 0..30.
    // Staging: A0:(t+1,q1)->b1 B0:(t+1,q2)->b1 C0:(t+1,q3)->b1 D0:(t+2,q0)->b0+VMW(2)
    //          A1:(t+2,q1)->b0 B1:(t+2,q2)->b0 C1:(t+2,q3)->b0 D1:(t+3,q0)->b1+VMW(2)
    // Every phase stages the OPPOSITE parity from what it reads (NoAlias).
    for (int i = 0; i < 31; ++i) {
        int t = 2 * i;
        // A0
        RD_A03_B01(0); STAGEQ_(1, t + 1, 1); LGKM8();
        BARRIER(); QUAD(0, 0); BARRIER();
        // B0
        RD_B23(0); STAGEQ_(1, t + 1, 2);
        BARRIER(); QUAD(0, 2); BARRIER();
        // C0
        RD_A47(0); STAGEQ_(1, t + 1, 3);
        BARRIER(); QUAD(4, 2); BARRIER();
        // D0: stage (t+2,q0)->buf0; VMW(2) retires tile t+1's 8 loads
        STAGEQ_(0, t + 2, 0); VMW(2);
        BARRIER(); QUAD(4, 0); BARRIER();
        // A1
        RD_A03_B01(1); STAGEQ_(0, t + 2, 1); LGKM8();
        BARRIER(); QUAD(0, 0); BARRIER();
        // B1
        RD_B23(1); STAGEQ_(0, t + 2, 2);
        BARRIER(); QUAD(0, 2); BARRIER();
        // C1
        RD_A47(1); STAGEQ_(0, t + 2, 3);
        BARRIER(); QUAD(4, 2); BARRIER();
        // D1: stage (t+3,q0)->buf1; VMW(2) retires tile t+2's 8 loads
        STAGEQ_(1, t + 3, 0); VMW(2);
        BARRIER(); QUAD(4, 0); BARRIER();
    }

    // peeled last pair (tiles 62 in buf0, 63 in buf1); finish staging 63->buf1
    RD_A03_B01(0); STAGEQ_(1, 63, 1); LGKM8();
    BARRIER(); QUAD(0, 0); BARRIER();
    RD_B23(0); STAGEQ_(1, 63, 2);
    BARRIER(); QUAD(0, 2); BARRIER();
    RD_A47(0); STAGEQ_(1, 63, 3);
    BARRIER(); QUAD(4, 2); BARRIER();
    VMW(0);                                  // drain: tile 63 complete
    BARRIER(); QUAD(4, 0); BARRIER();
    RD_A03_B01(1); BARRIER(); QUAD(0, 0); BARRIER();
    RD_B23(1);     BARRIER(); QUAD(0, 2); BARRIER();
    RD_A47(1);     BARRIER(); QUAD(4, 2); BARRIER();
    QUAD(4, 0);

    // epilogue: C/D layout col = lane&15, row = (lane>>4)*4 + jj
#pragma unroll
    for (int n = 0; n < 4; ++n) {
        int gcol = colBase + wn * 64 + n * 16 + frow;
        float bv = bias[gcol];
#pragma unroll
        for (int m = 0; m < 8; ++m) {
            int grow0 = rowBase + wm * 128 + m * 16 + g * 4;
#pragma unroll
            for (int jj = 0; jj < 4; ++jj)
                out[(size_t)(grow0 + jj) * OUT_F + gcol] = acc[m][n][jj] + bv;
        }
    }
}

// ---------- launch ----------
extern "C" void kernel_launch(void* const* d_in, const int* in_sizes, int n_in,
                              void* d_out, int out_size, void* d_ws, size_t ws_size,
                              hipStream_t stream) {
    const float* x         = (const float*)d_in[0];
    const int*   codes     = (const int*)d_in[1];
    const float* codebooks = (const float*)d_in[2];
    const float* scales    = (const float*)d_in[3];
    const float* bias      = (const float*)d_in[4];
    float* out = (float*)d_out;

    // workspace: Wq bf16 [OUT_F][IN_F], Xq bf16 [M_TOK][IN_F] = 157,286,400 B
    unsigned short* Wq = (unsigned short*)d_ws;
    unsigned short* Xq = (unsigned short*)((char*)d_ws + (size_t)OUT_F * IN_F * 2);

    k_dequant<<<NGRP / 256, 256, 0, stream>>>(codes, codebooks, scales, Wq);
    k_cvt<<<(M_TOK * IN_F / 8) / 256, 256, 0, stream>>>(x, Xq);
    // grid: (8192/256) * (11008/256) = 32 * 43 = 1376 blocks, 512 threads
    k_gemm<<<1376, 512, 0, stream>>>(Xq, Wq, bias, out);
}

// Round 10
// 796.510 us; speedup vs baseline: 1.1340x; 1.1340x over previous
//
#include <hip/hip_runtime.h>
#include <hip/hip_bf16.h>
#include <stdint.h>

// Problem constants (QuantizedLinear_15985868276124)
#define IN_F   4096
#define OUT_F  11008
#define M_TOK  8192                  // 4 * 2048 tokens
#define NGRP   (OUT_F * (IN_F / 8)) // 5,636,096 groups of 8 weights

typedef __attribute__((ext_vector_type(8))) short short8;
typedef __attribute__((ext_vector_type(4))) float f32x4;

// ---------- helpers ----------

__device__ __forceinline__ unsigned short bf16_rne(float f) {
    union { float f; uint32_t u; } v; v.f = f;
    uint32_t r = v.u + 0x7FFFu + ((v.u >> 16) & 1u); // round-to-nearest-even
    return (unsigned short)(r >> 16);
}

// ---------- kernel 1: dequantize W -> bf16 [OUT_F][IN_F] ----------
__global__ __launch_bounds__(256) void k_dequant(
        const int* __restrict__ codes,
        const float* __restrict__ codebooks,
        const float* __restrict__ scales,
        unsigned short* __restrict__ Wq) {
    __shared__ float cb[4096]; // [2][256][8]
    int tid = threadIdx.x;
    const float4* cbg = (const float4*)codebooks;
    float4* cbl = (float4*)cb;
#pragma unroll
    for (int i = 0; i < 4; ++i) cbl[tid + i * 256] = cbg[tid + i * 256];
    __syncthreads();

    int gidx = blockIdx.x * 256 + tid;      // group index in [0, NGRP)
    int o = gidx >> 9;                      // / 512
    float s = scales[o];
    int2 c = ((const int2*)codes)[gidx];

    const float4* e0 = (const float4*)&cb[c.x * 8];
    const float4* e1 = (const float4*)&cb[2048 + c.y * 8];
    float4 a0 = e0[0], a1 = e0[1];
    float4 b0 = e1[0], b1 = e1[1];

    float r[8];
    r[0] = (a0.x + b0.x) * s; r[1] = (a0.y + b0.y) * s;
    r[2] = (a0.z + b0.z) * s; r[3] = (a0.w + b0.w) * s;
    r[4] = (a1.x + b1.x) * s; r[5] = (a1.y + b1.y) * s;
    r[6] = (a1.z + b1.z) * s; r[7] = (a1.w + b1.w) * s;

    uint4 pk;
    pk.x = (uint32_t)bf16_rne(r[0]) | ((uint32_t)bf16_rne(r[1]) << 16);
    pk.y = (uint32_t)bf16_rne(r[2]) | ((uint32_t)bf16_rne(r[3]) << 16);
    pk.z = (uint32_t)bf16_rne(r[4]) | ((uint32_t)bf16_rne(r[5]) << 16);
    pk.w = (uint32_t)bf16_rne(r[6]) | ((uint32_t)bf16_rne(r[7]) << 16);
    *(uint4*)(Wq + (size_t)gidx * 8) = pk;
}

// ---------- kernel 2: x fp32 -> bf16 ----------
__global__ __launch_bounds__(256) void k_cvt(
        const float* __restrict__ x, unsigned short* __restrict__ Xq) {
    size_t i = ((size_t)blockIdx.x * 256 + threadIdx.x) * 8;
    float4 v0 = *(const float4*)(x + i);
    float4 v1 = *(const float4*)(x + i + 4);
    uint4 pk;
    pk.x = (uint32_t)bf16_rne(v0.x) | ((uint32_t)bf16_rne(v0.y) << 16);
    pk.y = (uint32_t)bf16_rne(v0.z) | ((uint32_t)bf16_rne(v0.w) << 16);
    pk.z = (uint32_t)bf16_rne(v1.x) | ((uint32_t)bf16_rne(v1.y) << 16);
    pk.w = (uint32_t)bf16_rne(v1.z) | ((uint32_t)bf16_rne(v1.w) << 16);
    *(uint4*)(Xq + i) = pk;
}

// ---------- kernel 3: 256x256 8-phase GEMM  C = Xq * Wq^T + bias ----------
// BM=BN=256, BK=64, 8 waves (2Mx4N), LDS 128 KiB (4 static buffers).
// R9 KEY: deep staging stagger. Quarters of tile t+2 staged at their
// earliest WAR-safe phases: q2,q3 (B halves, last read in phase B) at
// C(t); q0,q1 (A halves, last read in phase C) at D(t). The vmcnt(8)
// wait at D(t+1) is then >= 4 phases (~830 cyc) after the newest load
// it retires -- covering HBM latency. R4-R8 all staged the last quarter
// 1 phase before the wait (~200cyc) => exposed L3/HBM latency at every
// D-phase, schedule-invariant 859us / 37% MfmaUtil.

#define BARRIER() __builtin_amdgcn_s_barrier()
#define VMW(n)    asm volatile("s_waitcnt vmcnt(" #n ")")
#define LGKM8()   asm volatile("s_waitcnt lgkmcnt(8)")

#define GL16(gp, lp) __builtin_amdgcn_global_load_lds(                        \
    (const __attribute__((address_space(1))) void*)(gp),                      \
    (__attribute__((address_space(3))) void*)(lp), 16, 0, 0)

__global__ __launch_bounds__(512, 2) void k_gemm(
        const unsigned short* __restrict__ A,   // [M_TOK][IN_F] bf16
        const unsigned short* __restrict__ B,   // [OUT_F][IN_F] bf16 (B^T layout)
        const float* __restrict__ bias,
        float* __restrict__ out) {
    __shared__ unsigned short lA0[256 * 64];   // 32 KiB each
    __shared__ unsigned short lA1[256 * 64];
    __shared__ unsigned short lB0[256 * 64];
    __shared__ unsigned short lB1[256 * 64];

    const int tid = threadIdx.x;
    const int l = tid & 63;
    const int w = tid >> 6;            // wave 0..7
    const int wm = w >> 2, wn = w & 3; // 2 x 4 wave grid; wave tile 128x64

    // T1: bijective XCD swizzle. grid 1376 = 8 XCD * (4 row-chunks * 43 cols)
    int lid = blockIdx.x;
    int xcd = lid & 7, j = lid >> 3;   // j in [0,172)
    int bx = j >> 2;                   // col block 0..42 (column-major in chunk)
    int by = (xcd << 2) + (j & 3);     // row block 0..31
    const int rowBase = by * 256;
    const int colBase = bx * 256;

    // ---- staging addressing (T2: swizzle applied on GLOBAL source; LDS linear)
    // instr covers 64 rows: row = base + w*8 + (l>>3); LDS(r,cc)=global(r, cc^(r&7))
    const int srow = w * 8 + (l >> 3);
    const int scol = ((l & 7) ^ ((l >> 3) & 7)) << 3;   // swizzled element col
    const unsigned short* gA = A + (size_t)(rowBase + srow) * IN_F + scol;
    const unsigned short* gB = B + (size_t)(colBase + srow) * IN_F + scol;
    unsigned short* lA0w = &lA0[w * 8 * 64];
    unsigned short* lA1w = &lA1[w * 8 * 64];
    unsigned short* lB0w = &lB0[w * 8 * 64];
    unsigned short* lB1w = &lB1[w * 8 * 64];

    // stage one quarter of tile t into buffer P (STATIC):
    // q0/q1 = A rows {0-127, 128-255}; q2/q3 = B same
#define STAGEQ_(P, t, q) do {                                                 \
    const unsigned short* _g = (((q) < 2) ? gA : gB) + (size_t)(t) * 64;      \
    unsigned short* _l = (((q) < 2) ? lA##P##w : lB##P##w);                   \
    const int _r = ((q) & 1) * 128;                                           \
    GL16(_g + (size_t)_r * IN_F,        _l + _r * 64);                        \
    GL16(_g + (size_t)(_r + 64) * IN_F, _l + (_r + 64) * 64);                 \
} while (0)

    // ---- fragment reads (swizzled chunk = (kk*4+g) ^ (row&7), row&7 == frow&7)
    const int frow = l & 15, g = l >> 4;
    const int cho0 = ((g ^ (frow & 7)) << 4);
    const int cho1 = (((4 + g) ^ (frow & 7)) << 4);
    const char* rowA0 = (const char*)&lA0[(wm * 128 + frow) * 64];
    const char* rowA1 = (const char*)&lA1[(wm * 128 + frow) * 64];
    const char* rowB0 = (const char*)&lB0[(wn * 64 + frow) * 64];
    const char* rowB1 = (const char*)&lB1[(wn * 64 + frow) * 64];
#define LDA_(P, m, kk) (*(const short8*)(rowA##P + (m) * 2048 + ((kk) ? cho1 : cho0)))
#define LDB_(P, n, kk) (*(const short8*)(rowB##P + (n) * 2048 + ((kk) ? cho1 : cho0)))

    f32x4 acc[8][4] = {};
    short8 ar[4][2], br[4][2];

#define QUAD(M0, N0) do {                                                     \
    __builtin_amdgcn_s_setprio(1);                                            \
    _Pragma("unroll") for (int mm = 0; mm < 4; ++mm)                          \
    _Pragma("unroll") for (int nn = 0; nn < 2; ++nn)                          \
    _Pragma("unroll") for (int kk = 0; kk < 2; ++kk)                          \
        acc[(M0) + mm][(N0) + nn] = __builtin_amdgcn_mfma_f32_16x16x32_bf16(  \
            ar[mm][kk], br[(N0) + nn][kk], acc[(M0) + mm][(N0) + nn], 0, 0, 0);\
    __builtin_amdgcn_s_setprio(0);                                            \
} while (0)

#define RD_A03_B01(P) do {                                                    \
    _Pragma("unroll") for (int mm = 0; mm < 4; ++mm) {                        \
        ar[mm][0] = LDA_(P, mm, 0); ar[mm][1] = LDA_(P, mm, 1); }             \
    br[0][0] = LDB_(P, 0, 0); br[0][1] = LDB_(P, 0, 1);                       \
    br[1][0] = LDB_(P, 1, 0); br[1][1] = LDB_(P, 1, 1);                       \
} while (0)
#define RD_B23(P) do {                                                        \
    br[2][0] = LDB_(P, 2, 0); br[2][1] = LDB_(P, 2, 1);                       \
    br[3][0] = LDB_(P, 3, 0); br[3][1] = LDB_(P, 3, 1);                       \
} while (0)
#define RD_A47(P) do {                                                        \
    _Pragma("unroll") for (int mm = 0; mm < 4; ++mm) {                        \
        ar[mm][0] = LDA_(P, 4 + mm, 0); ar[mm][1] = LDA_(P, 4 + mm, 1); }     \
} while (0)

    // prologue: stage tile0 fully (buf0), then tile1 in C/D order (q2,q3,q0,q1)
    // FIFO = t0(8), t1q23(4), t1q01(4); VMW(8) retires t0's 8 -> tile0 ready.
    STAGEQ_(0, 0, 0); STAGEQ_(0, 0, 1); STAGEQ_(0, 0, 2); STAGEQ_(0, 0, 3);
    STAGEQ_(1, 1, 2); STAGEQ_(1, 1, 3); STAGEQ_(1, 1, 0); STAGEQ_(1, 1, 1);
    VMW(8); BARRIER();

    // main loop: 2 K-tiles/iter (t=2i in buf0, t+1 in buf1); i = 0..30.
    // Stagger: C0: t+2 q2,q3 (B; WAR-safe after B0's closing barrier)
    //          D0: t+2 q0,q1 (A; WAR-safe after C0's closing barrier) + VMW(8)
    //          C1/D1 mirror for t+3. VMW(8) at D retires the tile read NEXT
    //          phase; its newest load was issued 4 phases (~830cyc) earlier.
    for (int i = 0; i < 31; ++i) {
        int t = 2 * i;
        // A0
        RD_A03_B01(0); LGKM8();
        BARRIER(); QUAD(0, 0); BARRIER();
        // B0
        RD_B23(0);
        BARRIER(); QUAD(0, 2); BARRIER();
        // C0: stage B-half of t+2 into buf0
        RD_A47(0); STAGEQ_(0, t + 2, 2); STAGEQ_(0, t + 2, 3);
        BARRIER(); QUAD(4, 2); BARRIER();
        // D0: stage A-half of t+2; VMW(8) retires tile t+1's 8 loads
        STAGEQ_(0, t + 2, 0); STAGEQ_(0, t + 2, 1); VMW(8);
        BARRIER(); QUAD(4, 0); BARRIER();
        // A1
        RD_A03_B01(1); LGKM8();
        BARRIER(); QUAD(0, 0); BARRIER();
        // B1
        RD_B23(1);
        BARRIER(); QUAD(0, 2); BARRIER();
        // C1: stage B-half of t+3 into buf1
        RD_A47(1); STAGEQ_(1, t + 3, 2); STAGEQ_(1, t + 3, 3);
        BARRIER(); QUAD(4, 2); BARRIER();
        // D1: stage A-half of t+3; VMW(8) retires tile t+2's 8 loads
        STAGEQ_(1, t + 3, 0); STAGEQ_(1, t + 3, 1); VMW(8);
        BARRIER(); QUAD(4, 0); BARRIER();
    }

    // peeled last pair (tiles 62 in buf0, 63 in buf1); no new staging
    RD_A03_B01(0); LGKM8();
    BARRIER(); QUAD(0, 0); BARRIER();
    RD_B23(0);
    BARRIER(); QUAD(0, 2); BARRIER();
    RD_A47(0);
    BARRIER(); QUAD(4, 2); BARRIER();
    VMW(0);                                  // drain: tile 63 complete
    BARRIER(); QUAD(4, 0); BARRIER();
    RD_A03_B01(1); BARRIER(); QUAD(0, 0); BARRIER();
    RD_B23(1);     BARRIER(); QUAD(0, 2); BARRIER();
    RD_A47(1);     BARRIER(); QUAD(4, 2); BARRIER();
    QUAD(4, 0);

    // epilogue: C/D layout col = lane&15, row = (lane>>4)*4 + jj
#pragma unroll
    for (int n = 0; n < 4; ++n) {
        int gcol = colBase + wn * 64 + n * 16 + frow;
        float bv = bias[gcol];
#pragma unroll
        for (int m = 0; m < 8; ++m) {
            int grow0 = rowBase + wm * 128 + m * 16 + g * 4;
#pragma unroll
            for (int jj = 0; jj < 4; ++jj)
                out[(size_t)(grow0 + jj) * OUT_F + gcol] = acc[m][n][jj] + bv;
        }
    }
}

// ---------- launch ----------
extern "C" void kernel_launch(void* const* d_in, const int* in_sizes, int n_in,
                              void* d_out, int out_size, void* d_ws, size_t ws_size,
                              hipStream_t stream) {
    const float* x         = (const float*)d_in[0];
    const int*   codes     = (const int*)d_in[1];
    const float* codebooks = (const float*)d_in[2];
    const float* scales    = (const float*)d_in[3];
    const float* bias      = (const float*)d_in[4];
    float* out = (float*)d_out;

    // workspace: Wq bf16 [OUT_F][IN_F], Xq bf16 [M_TOK][IN_F] = 157,286,400 B
    unsigned short* Wq = (unsigned short*)d_ws;
    unsigned short* Xq = (unsigned short*)((char*)d_ws + (size_t)OUT_F * IN_F * 2);

    k_dequant<<<NGRP / 256, 256, 0, stream>>>(codes, codebooks, scales, Wq);
    k_cvt<<<(M_TOK * IN_F / 8) / 256, 256, 0, stream>>>(x, Xq);
    // grid: (8192/256) * (11008/256) = 32 * 43 = 1376 blocks, 512 threads
    k_gemm<<<1376, 512, 0, stream>>>(Xq, Wq, bias, out);
}